// Round 1
// baseline (1081.300 us; speedup 1.0000x reference)
//
#include <hip/hip_runtime.h>
#include <hip/hip_bf16.h>

#define T_STEPS 2048
#define BATCH 16
#define DIM 1024
#define EPSV 1e-6f

typedef short short8 __attribute__((ext_vector_type(8)));
typedef float f32x4 __attribute__((ext_vector_type(4)));

struct alignas(16) bf16x8pack { __hip_bfloat16 v[8]; };

// ---------------- fp32 -> bf16 convert (vectorized) ----------------
__global__ __launch_bounds__(256) void cvt_kernel(const float* __restrict__ src,
                                                  bf16x8pack* __restrict__ dst, int n8) {
  int i = blockIdx.x * blockDim.x + threadIdx.x;
  if (i >= n8) return;
  const float4* s4 = (const float4*)src + (size_t)i * 2;
  float4 a = s4[0];
  float4 b = s4[1];
  bf16x8pack p;
  p.v[0] = __float2bfloat16(a.x); p.v[1] = __float2bfloat16(a.y);
  p.v[2] = __float2bfloat16(a.z); p.v[3] = __float2bfloat16(a.w);
  p.v[4] = __float2bfloat16(b.x); p.v[5] = __float2bfloat16(b.y);
  p.v[6] = __float2bfloat16(b.z); p.v[7] = __float2bfloat16(b.w);
  dst[i] = p;
}

// ---------------- bf16 MFMA GEMM: Wx[m][e] = sum_d X[m][d]*W[e][d] + b[e] ----------------
// 128x128 tile, BK=32, 256 threads (4 waves, 2x2), m97-style global_load_lds staging.
// Output written to hreg[(m+16)*1024 + e]  (slot t+1 staging for the scan).
__global__ __launch_bounds__(256) void gemm_kernel(
    const __hip_bfloat16* __restrict__ Xb,
    const __hip_bfloat16* __restrict__ Wb,
    const float* __restrict__ bias,
    float* __restrict__ hreg) {
  __shared__ __hip_bfloat16 As[128 * 32];
  __shared__ __hip_bfloat16 Bs[128 * 32];
  const int tid = threadIdx.x;
  const int wave = tid >> 6, lane = tid & 63;
  const int m0 = blockIdx.y * 128;
  const int e0 = blockIdx.x * 128;
  const int wm = (wave >> 1) * 64;
  const int wn = (wave & 1) * 64;
  const int l15 = lane & 15, l4 = lane >> 4;

  f32x4 acc[4][4] = {};

  const int srow = wave * 16 + (lane >> 2);   // staging row within 64-row group
  const int sch = (lane & 3) * 8;             // 8 bf16 = 16B chunk

  for (int kt = 0; kt < DIM; kt += 32) {
    __syncthreads();
#pragma unroll
    for (int i = 0; i < 2; ++i) {
      const __hip_bfloat16* ga = Xb + (size_t)(m0 + i * 64 + srow) * DIM + kt + sch;
      const __hip_bfloat16* gb = Wb + (size_t)(e0 + i * 64 + srow) * DIM + kt + sch;
      __builtin_amdgcn_global_load_lds(
          (const __attribute__((address_space(1))) void*)ga,
          (__attribute__((address_space(3))) void*)((char*)As + (i * 64 + wave * 16) * 64),
          16, 0, 0);
      __builtin_amdgcn_global_load_lds(
          (const __attribute__((address_space(1))) void*)gb,
          (__attribute__((address_space(3))) void*)((char*)Bs + (i * 64 + wave * 16) * 64),
          16, 0, 0);
    }
    __syncthreads();
    short8 a[4], b[4];
#pragma unroll
    for (int f = 0; f < 4; ++f)
      a[f] = *(const short8*)((const char*)As + ((wm + f * 16 + l15) * 32 + l4 * 8) * 2);
#pragma unroll
    for (int g = 0; g < 4; ++g)
      b[g] = *(const short8*)((const char*)Bs + ((wn + g * 16 + l15) * 32 + l4 * 8) * 2);
#pragma unroll
    for (int f = 0; f < 4; ++f)
#pragma unroll
      for (int g = 0; g < 4; ++g)
        acc[f][g] = __builtin_amdgcn_mfma_f32_16x16x32_bf16(a[f], b[g], acc[f][g], 0, 0, 0);
  }
  // epilogue: D mapping col = lane&15, row = (lane>>4)*4 + r  [m89-verified]
#pragma unroll
  for (int g = 0; g < 4; ++g) {
    const int e = e0 + wn + g * 16 + l15;
    const float bv = bias[e];
#pragma unroll
    for (int f = 0; f < 4; ++f) {
#pragma unroll
      for (int r = 0; r < 4; ++r) {
        const int m = m0 + wm + f * 16 + l4 * 4 + r;
        hreg[(size_t)(m + BATCH) * DIM + e] = acc[f][g][r] + bv;
      }
    }
  }
}

// ---------------- sequential scan: h_t = rms_norm(h_{t-1} + alpha*wx_t) ----------------
// 16 blocks (one per batch row), 1 wave each. Wx staged in hreg slot t+1; we read it
// then overwrite the slot with h_t. No __syncthreads anywhere (wave-synchronous).
__global__ __launch_bounds__(64) void scan_kernel(
    const float* __restrict__ h0,
    const float* __restrict__ log_alpha_p,
    float* __restrict__ hreg) {
  const int b = blockIdx.x;
  const int lane = threadIdx.x;
  const float alpha = expf(log_alpha_p[0]);
  const float4* h04 = (const float4*)h0;
  float4* h4 = (float4*)hreg;
  const int base = b * 256 + lane;             // float4 index within a [B][D] slot
  const size_t SLOT4 = (size_t)BATCH * DIM / 4;  // 4096 float4 per slot

  float4 h[4], wxa[4], wxb[4];
#pragma unroll
  for (int j = 0; j < 4; ++j) h[j] = h04[base + 64 * j];
#pragma unroll
  for (int j = 0; j < 4; ++j) h4[base + 64 * j] = h[j];  // h[0] = h0
#pragma unroll
  for (int j = 0; j < 4; ++j) wxa[j] = h4[SLOT4 + base + 64 * j];       // wx_0
#pragma unroll
  for (int j = 0; j < 4; ++j) wxb[j] = h4[2 * SLOT4 + base + 64 * j];   // wx_1

#pragma unroll 2
  for (int t = 0; t < T_STEPS; ++t) {
    float4 s[4];
    float p0 = 0.f, p1 = 0.f, p2 = 0.f, p3 = 0.f;
#pragma unroll
    for (int j = 0; j < 4; ++j) {
      s[j].x = fmaf(alpha, wxa[j].x, h[j].x);
      s[j].y = fmaf(alpha, wxa[j].y, h[j].y);
      s[j].z = fmaf(alpha, wxa[j].z, h[j].z);
      s[j].w = fmaf(alpha, wxa[j].w, h[j].w);
      p0 = fmaf(s[j].x, s[j].x, p0);
      p1 = fmaf(s[j].y, s[j].y, p1);
      p2 = fmaf(s[j].z, s[j].z, p2);
      p3 = fmaf(s[j].w, s[j].w, p3);
    }
    float sum = (p0 + p1) + (p2 + p3);
#pragma unroll
    for (int off = 32; off; off >>= 1) sum += __shfl_xor(sum, off, 64);
    // store h_{t-1} (independent of the in-flight reduce)
    if (t > 0) {
#pragma unroll
      for (int j = 0; j < 4; ++j) h4[SLOT4 * (size_t)t + base + 64 * j] = h[j];
    }
    // rotate + prefetch wx_{t+2} (slot t+3)
#pragma unroll
    for (int j = 0; j < 4; ++j) wxa[j] = wxb[j];
    if (t < T_STEPS - 2) {
#pragma unroll
      for (int j = 0; j < 4; ++j) wxb[j] = h4[SLOT4 * (size_t)(t + 3) + base + 64 * j];
    }
    float rinv = rsqrtf(sum * (1.0f / DIM) + EPSV);
#pragma unroll
    for (int j = 0; j < 4; ++j) {
      h[j].x = s[j].x * rinv; h[j].y = s[j].y * rinv;
      h[j].z = s[j].z * rinv; h[j].w = s[j].w * rinv;
    }
  }
#pragma unroll
  for (int j = 0; j < 4; ++j) h4[SLOT4 * (size_t)T_STEPS + base + 64 * j] = h[j];
}

// ---------------- outs[t] = h_{t+1} * silu(h_{t+1}) -- massively parallel ----------------
__global__ __launch_bounds__(256) void silu_kernel(const float4* __restrict__ hsrc,
                                                   float4* __restrict__ out4, int n4) {
  int i = blockIdx.x * blockDim.x + threadIdx.x;
  if (i >= n4) return;
  float4 h = hsrc[i];
  float4 o;
  o.x = h.x * h.x / (1.f + __expf(-h.x));
  o.y = h.y * h.y / (1.f + __expf(-h.y));
  o.z = h.z * h.z / (1.f + __expf(-h.z));
  o.w = h.w * h.w / (1.f + __expf(-h.w));
  out4[i] = o;
}

extern "C" void kernel_launch(void* const* d_in, const int* in_sizes, int n_in,
                              void* d_out, int out_size, void* d_ws, size_t ws_size,
                              hipStream_t stream) {
  (void)in_sizes; (void)n_in; (void)d_ws; (void)ws_size; (void)out_size;
  const float* x = (const float*)d_in[0];
  const float* h0 = (const float*)d_in[1];
  const float* W = (const float*)d_in[2];
  const float* bias = (const float*)d_in[3];
  const float* log_alpha = (const float*)d_in[4];

  float* out = (float*)d_out;                                  // outs region [T][B][D]
  float* hreg = out + (size_t)T_STEPS * BATCH * DIM;           // h region [T+1][B][D]
  // bf16 staging overlays the outs region (fully consumed before scan overwrites it)
  __hip_bfloat16* xb = (__hip_bfloat16*)d_out;
  __hip_bfloat16* wb = (__hip_bfloat16*)((char*)d_out + (size_t)T_STEPS * BATCH * DIM * 2);

  const int nx8 = T_STEPS * BATCH * DIM / 8;   // 4,194,304
  const int nw8 = DIM * DIM / 8;               // 131,072
  cvt_kernel<<<nx8 / 256, 256, 0, stream>>>(x, (bf16x8pack*)xb, nx8);
  cvt_kernel<<<nw8 / 256, 256, 0, stream>>>(W, (bf16x8pack*)wb, nw8);

  dim3 ggrid(DIM / 128, (T_STEPS * BATCH) / 128);              // (8, 256)
  gemm_kernel<<<ggrid, 256, 0, stream>>>(xb, wb, bias, hreg);

  scan_kernel<<<BATCH, 64, 0, stream>>>(h0, log_alpha, hreg);

  const int n4 = T_STEPS * BATCH * DIM / 4;                    // 8,388,608
  silu_kernel<<<n4 / 256, 256, 0, stream>>>((const float4*)(hreg + BATCH * DIM),
                                            (float4*)out, n4);
}

// Round 2
// 583.549 us; speedup vs baseline: 1.8530x; 1.8530x over previous
//
#include <hip/hip_runtime.h>
#include <hip/hip_bf16.h>

#define T_STEPS 2048
#define BATCH 16
#define DIM 1024
#define EPSV 1e-6f

typedef short short8 __attribute__((ext_vector_type(8)));
typedef float f32x4 __attribute__((ext_vector_type(4)));

struct alignas(16) bf16x8pack { __hip_bfloat16 v[8]; };

// ---------------- fp32 -> bf16 convert (vectorized) ----------------
__global__ __launch_bounds__(256) void cvt_kernel(const float* __restrict__ src,
                                                  bf16x8pack* __restrict__ dst, int n8) {
  int i = blockIdx.x * blockDim.x + threadIdx.x;
  if (i >= n8) return;
  const float4* s4 = (const float4*)src + (size_t)i * 2;
  float4 a = s4[0];
  float4 b = s4[1];
  bf16x8pack p;
  p.v[0] = __float2bfloat16(a.x); p.v[1] = __float2bfloat16(a.y);
  p.v[2] = __float2bfloat16(a.z); p.v[3] = __float2bfloat16(a.w);
  p.v[4] = __float2bfloat16(b.x); p.v[5] = __float2bfloat16(b.y);
  p.v[6] = __float2bfloat16(b.z); p.v[7] = __float2bfloat16(b.w);
  dst[i] = p;
}

// ---------------- bf16 MFMA GEMM: out[m][e] = alpha*(sum_d X[m][d]*W[e][d] + b[e]) ----
// 128x128 tile, BK=32, 256 threads (4 waves, 2x2), m97-style global_load_lds staging.
// Output written to hreg[(m+16)*1024 + e]  (slot t+1 staging for the scan),
// pre-scaled by alpha so the scan never multiplies by alpha.
__global__ __launch_bounds__(256) void gemm_kernel(
    const __hip_bfloat16* __restrict__ Xb,
    const __hip_bfloat16* __restrict__ Wb,
    const float* __restrict__ bias,
    const float* __restrict__ log_alpha_p,
    float* __restrict__ hreg) {
  __shared__ __hip_bfloat16 As[128 * 32];
  __shared__ __hip_bfloat16 Bs[128 * 32];
  const int tid = threadIdx.x;
  const int wave = tid >> 6, lane = tid & 63;
  const int m0 = blockIdx.y * 128;
  const int e0 = blockIdx.x * 128;
  const int wm = (wave >> 1) * 64;
  const int wn = (wave & 1) * 64;
  const int l15 = lane & 15, l4 = lane >> 4;

  f32x4 acc[4][4] = {};

  const int srow = wave * 16 + (lane >> 2);   // staging row within 64-row group
  const int sch = (lane & 3) * 8;             // 8 bf16 = 16B chunk

  for (int kt = 0; kt < DIM; kt += 32) {
    __syncthreads();
#pragma unroll
    for (int i = 0; i < 2; ++i) {
      const __hip_bfloat16* ga = Xb + (size_t)(m0 + i * 64 + srow) * DIM + kt + sch;
      const __hip_bfloat16* gb = Wb + (size_t)(e0 + i * 64 + srow) * DIM + kt + sch;
      __builtin_amdgcn_global_load_lds(
          (const __attribute__((address_space(1))) void*)ga,
          (__attribute__((address_space(3))) void*)((char*)As + (i * 64 + wave * 16) * 64),
          16, 0, 0);
      __builtin_amdgcn_global_load_lds(
          (const __attribute__((address_space(1))) void*)gb,
          (__attribute__((address_space(3))) void*)((char*)Bs + (i * 64 + wave * 16) * 64),
          16, 0, 0);
    }
    __syncthreads();
    short8 a[4], b[4];
#pragma unroll
    for (int f = 0; f < 4; ++f)
      a[f] = *(const short8*)((const char*)As + ((wm + f * 16 + l15) * 32 + l4 * 8) * 2);
#pragma unroll
    for (int g = 0; g < 4; ++g)
      b[g] = *(const short8*)((const char*)Bs + ((wn + g * 16 + l15) * 32 + l4 * 8) * 2);
#pragma unroll
    for (int f = 0; f < 4; ++f)
#pragma unroll
      for (int g = 0; g < 4; ++g)
        acc[f][g] = __builtin_amdgcn_mfma_f32_16x16x32_bf16(a[f], b[g], acc[f][g], 0, 0, 0);
  }
  const float alpha = __expf(log_alpha_p[0]);
  // epilogue: D mapping col = lane&15, row = (lane>>4)*4 + r  [m89-verified]
#pragma unroll
  for (int g = 0; g < 4; ++g) {
    const int e = e0 + wn + g * 16 + l15;
    const float bv = bias[e];
#pragma unroll
    for (int f = 0; f < 4; ++f) {
#pragma unroll
      for (int r = 0; r < 4; ++r) {
        const int m = m0 + wm + f * 16 + l4 * 4 + r;
        hreg[(size_t)(m + BATCH) * DIM + e] = alpha * (acc[f][g][r] + bv);
      }
    }
  }
}

// ---------------- wave-wide sum via DPP (no LDS pipe, ~12 VALU ops) ----------------
__device__ __forceinline__ float wave_sum_dpp(float x) {
  float acc = x;
#define DPP_ADD(ctrl)                                                              \
  {                                                                                \
    int t_ = __builtin_amdgcn_update_dpp(0, __float_as_int(acc), (ctrl), 0xf, 0xf, \
                                         true);                                    \
    acc += __int_as_float(t_);                                                     \
  }
  DPP_ADD(0x111);  // row_shr:1
  DPP_ADD(0x112);  // row_shr:2
  DPP_ADD(0x114);  // row_shr:4
  DPP_ADD(0x118);  // row_shr:8   -> lane 15/31/47/63 hold row sums
  DPP_ADD(0x142);  // row_bcast:15 -> lane 31 = rows0+1, lane 63 = rows2+3
  DPP_ADD(0x143);  // row_bcast:31 -> lane 63 = total
#undef DPP_ADD
  return __int_as_float(__builtin_amdgcn_readlane(__float_as_int(acc), 63));
}

// ---------------- sequential scan: h_t = rms_norm(h_{t-1} + alpha*wx_t) ----------------
// 16 blocks (one per batch row), 1 wave each.
// Deferred normalization: keep (s_t, rinv_t) with h_t = s_t * rinv_t.
//   s_{t+1} = rinv_t * s_t + awx_t        (awx pre-scaled by alpha in GEMM)
//   rinv_{t+1} = rsqrt(mean(s_{t+1}^2) + eps)
// h_t stores use OLD s/rinv -> off the critical chain, issued during reduce latency.
__global__ __launch_bounds__(64) void scan_kernel(
    const float* __restrict__ h0,
    float* __restrict__ hreg) {
  const int b = blockIdx.x;
  const int lane = threadIdx.x;
  const float4* h04 = (const float4*)h0;
  float4* h4 = (float4*)hreg;
  const int base = b * 256 + lane;               // float4 index within a [B][D] slot
  const size_t SLOT4 = (size_t)BATCH * DIM / 4;  // 4096 float4 per slot

  float4 s[4], wx[4][4];
#pragma unroll
  for (int j = 0; j < 4; ++j) s[j] = h04[base + 64 * j];
#pragma unroll
  for (int j = 0; j < 4; ++j) h4[base + 64 * j] = s[j];  // slot 0 = h0
  // preload awx_0..awx_3 (slots 1..4)
#pragma unroll
  for (int p = 0; p < 4; ++p)
#pragma unroll
    for (int j = 0; j < 4; ++j) wx[p][j] = h4[SLOT4 * (size_t)(p + 1) + base + 64 * j];

  float rinv = 1.0f;

#pragma unroll 4
  for (int t = 0; t < T_STEPS; ++t) {
    const int ph = t & 3;
    // critical chain: s_{t+1} = rinv_t*s_t + awx_t
    float4 sn[4];
    float p0 = 0.f, p1 = 0.f, p2 = 0.f, p3 = 0.f;
#pragma unroll
    for (int j = 0; j < 4; ++j) {
      sn[j].x = fmaf(rinv, s[j].x, wx[ph][j].x);
      sn[j].y = fmaf(rinv, s[j].y, wx[ph][j].y);
      sn[j].z = fmaf(rinv, s[j].z, wx[ph][j].z);
      sn[j].w = fmaf(rinv, s[j].w, wx[ph][j].w);
      p0 = fmaf(sn[j].x, sn[j].x, p0);
      p1 = fmaf(sn[j].y, sn[j].y, p1);
      p2 = fmaf(sn[j].z, sn[j].z, p2);
      p3 = fmaf(sn[j].w, sn[j].w, p3);
    }
    float sum = wave_sum_dpp((p0 + p1) + (p2 + p3));
    // dangling work (old s, old rinv): h_t = s_t * rinv_t -> slot t
    {
      float4 hv[4];
#pragma unroll
      for (int j = 0; j < 4; ++j) {
        hv[j].x = s[j].x * rinv; hv[j].y = s[j].y * rinv;
        hv[j].z = s[j].z * rinv; hv[j].w = s[j].w * rinv;
      }
      if (t > 0) {
#pragma unroll
        for (int j = 0; j < 4; ++j) h4[SLOT4 * (size_t)t + base + 64 * j] = hv[j];
      }
    }
    // prefetch awx_{t+4} (slot t+5) into the ring
    if (t + 4 < T_STEPS) {
#pragma unroll
      for (int j = 0; j < 4; ++j) wx[ph][j] = h4[SLOT4 * (size_t)(t + 5) + base + 64 * j];
    }
    rinv = rsqrtf(fmaf(sum, 1.0f / DIM, EPSV));
#pragma unroll
    for (int j = 0; j < 4; ++j) s[j] = sn[j];
  }
  // final: h_T = s_T * rinv_T -> slot T
#pragma unroll
  for (int j = 0; j < 4; ++j) {
    float4 hv;
    hv.x = s[j].x * rinv; hv.y = s[j].y * rinv;
    hv.z = s[j].z * rinv; hv.w = s[j].w * rinv;
    h4[SLOT4 * (size_t)T_STEPS + base + 64 * j] = hv;
  }
}

// ---------------- outs[t] = h_{t+1} * silu(h_{t+1}) -- massively parallel ----------------
__global__ __launch_bounds__(256) void silu_kernel(const float4* __restrict__ hsrc,
                                                   float4* __restrict__ out4, int n4) {
  int i = blockIdx.x * blockDim.x + threadIdx.x;
  if (i >= n4) return;
  float4 h = hsrc[i];
  float4 o;
  o.x = h.x * h.x / (1.f + __expf(-h.x));
  o.y = h.y * h.y / (1.f + __expf(-h.y));
  o.z = h.z * h.z / (1.f + __expf(-h.z));
  o.w = h.w * h.w / (1.f + __expf(-h.w));
  out4[i] = o;
}

extern "C" void kernel_launch(void* const* d_in, const int* in_sizes, int n_in,
                              void* d_out, int out_size, void* d_ws, size_t ws_size,
                              hipStream_t stream) {
  (void)in_sizes; (void)n_in; (void)d_ws; (void)ws_size; (void)out_size;
  const float* x = (const float*)d_in[0];
  const float* h0 = (const float*)d_in[1];
  const float* W = (const float*)d_in[2];
  const float* bias = (const float*)d_in[3];
  const float* log_alpha = (const float*)d_in[4];

  float* out = (float*)d_out;                                  // outs region [T][B][D]
  float* hreg = out + (size_t)T_STEPS * BATCH * DIM;           // h region [T+1][B][D]
  // bf16 staging overlays the outs region (fully consumed before scan overwrites it)
  __hip_bfloat16* xb = (__hip_bfloat16*)d_out;
  __hip_bfloat16* wb = (__hip_bfloat16*)((char*)d_out + (size_t)T_STEPS * BATCH * DIM * 2);

  const int nx8 = T_STEPS * BATCH * DIM / 8;   // 4,194,304
  const int nw8 = DIM * DIM / 8;               // 131,072
  cvt_kernel<<<nx8 / 256, 256, 0, stream>>>(x, (bf16x8pack*)xb, nx8);
  cvt_kernel<<<nw8 / 256, 256, 0, stream>>>(W, (bf16x8pack*)wb, nw8);

  dim3 ggrid(DIM / 128, (T_STEPS * BATCH) / 128);              // (8, 256)
  gemm_kernel<<<ggrid, 256, 0, stream>>>(xb, wb, bias, log_alpha, hreg);

  scan_kernel<<<BATCH, 64, 0, stream>>>(h0, hreg);

  const int n4 = T_STEPS * BATCH * DIM / 4;                    // 8,388,608
  silu_kernel<<<n4 / 256, 256, 0, stream>>>((const float4*)(hreg + BATCH * DIM),
                                            (float4*)out, n4);
}